// Round 7
// baseline (274.508 us; speedup 1.0000x reference)
//
#include <hip/hip_runtime.h>

#define B_ 32
#define N_ 1024
#define NEG 0.01f
#define QSC (1.4426950408889634f/32.0f)   // log2(e)/E folded into staged Wq/bq
#define MAGIC 0x5EEDBEA7u

using half8  = __attribute__((ext_vector_type(8))) _Float16;
using half4  = __attribute__((ext_vector_type(4))) _Float16;
using half2  = __attribute__((ext_vector_type(2))) _Float16;
using fp16x2 = __attribute__((ext_vector_type(2))) __fp16;
using floatx4 = __attribute__((ext_vector_type(4))) float;

#if defined(__has_builtin)
#if __has_builtin(__builtin_amdgcn_exp2f)
#define EXP2(x) __builtin_amdgcn_exp2f(x)
#endif
#endif
#ifndef EXP2
#define EXP2(x) exp2f(x)
#endif

#define MFMA32 __builtin_amdgcn_mfma_f32_16x16x32_f16
#define MFMA16 __builtin_amdgcn_mfma_f32_16x16x16f16

__device__ inline half2 pkcvt(float a, float b) {
    fp16x2 r = __builtin_amdgcn_cvt_pkrtz(a, b);
    return __builtin_bit_cast(half2, r);
}

__device__ inline half8 cvt8(float4 a, float4 b) {
    half2 p0 = pkcvt(a.x, a.y);
    half2 p1 = pkcvt(a.z, a.w);
    half2 p2 = pkcvt(b.x, b.y);
    half2 p3 = pkcvt(b.z, b.w);
    half8 h = { p0[0],p0[1], p1[0],p1[1], p2[0],p2[1], p3[0],p3[1] };
    return h;
}

// async global->LDS DMA: per-lane gptr, wave-uniform lptr; HW writes lptr+lane*16
__device__ __forceinline__ void gload16(const _Float16* g, _Float16* l) {
    __builtin_amdgcn_global_load_lds(
        (const __attribute__((address_space(1))) unsigned int*)g,
        (__attribute__((address_space(3))) unsigned int*)l, 16, 0, 0);
}

// Single REGULAR dispatch, 512 blocks x 256 thr, guaranteed 2 blocks/CU
// co-resident (launch_bounds(256,2), LDS 40.4KB). Producer/consumer handshake
// via per-(bg,qtile) MAGIC flags in workspace: release(threadfence + atomic
// store) after publishing own K/Vt slice; bounded acquire-spin before staging
// each tile. Device-scope atomics -> correct regardless of XCD placement.
// Phase 1: project ONLY own 128 rows (no 8x redundancy); K bias dropped
//          (softmax shift-invariant). Phase 2: attention with DMA-staged,
//          double-buffered, XOR-swizzled K/V tiles. Phase 3: MLP.
struct __align__(16) Smem {
    _Float16 wsh[96*36];
    float    bsh[96];
    union {
        struct { _Float16 qs[128*40]; _Float16 kst[128*32]; _Float16 vt[32*136]; } p1;
        struct { _Float16 K[2][4096]; _Float16 Vt[2][4096]; } p2;   // [128n][32e] / [32e][128n]
        _Float16 xs[128*72];       // MLP input [q][ v(32) | attn(32) ]
    } u;
    float bl1[32], bl10[32], bl11[32];
};  // 40448 B

__global__ __launch_bounds__(256, 2) void fused_kernel(
    const float* __restrict__ x, const float* __restrict__ w_qkv, const float* __restrict__ b_qkv,
    const float* __restrict__ w_h1,  const float* __restrict__ b_h1,
    const float* __restrict__ w_h10, const float* __restrict__ b_h10,
    const float* __restrict__ w_h11, const float* __restrict__ b_h11,
    float* __restrict__ out, _Float16* __restrict__ Kg, _Float16* __restrict__ Vtg,
    unsigned* __restrict__ flags)
{
    __shared__ Smem sm;
    int t = threadIdx.x;
    int bid = blockIdx.x;
    // XCD-affine remap: all 8 q-tile blocks of one bg land on the same XCD
    int xcd = bid & 7, j = bid >> 3;
    int bg = xcd*8 + (j >> 3);
    int qtile = j & 7;
    int b = bg >> 1, g = bg & 1;
    int qbase = qtile * 128;
    int lane = t & 63, w = t >> 6;
    int L15 = lane & 15, quad = lane >> 4;
    const floatx4 zz = {0.f,0.f,0.f,0.f};

    // ================= Phase 1: project own 128 rows =================
    for (int idx = t; idx < 96*32; idx += 256) {
        int r = idx >> 5, c = idx & 31;
        float wv = w_qkv[(g*96 + r)*32 + c];
        sm.wsh[r*36 + c] = (_Float16)(r < 32 ? wv*QSC : wv);
    }
    if (t < 96) sm.bsh[t] = b_qkv[g*96 + t];
    if (t < 32) {
        sm.bl1[t]  = b_h1[g*32+t];
        sm.bl10[t] = b_h10[g*32+t];
        sm.bl11[t] = b_h11[g*32+t];
    }
    __syncthreads();

    half8 bwq[2], bwk[2], bwv[2];
    float bqv[2], bvv[2];
    #pragma unroll
    for (int et = 0; et < 2; et++) {
        bwq[et] = *(const half8*)&sm.wsh[(     et*16 + L15)*36 + quad*8];
        bwk[et] = *(const half8*)&sm.wsh[(32 + et*16 + L15)*36 + quad*8];
        bwv[et] = *(const half8*)&sm.wsh[(64 + et*16 + L15)*36 + quad*8];
        bqv[et] = sm.bsh[     et*16 + L15] * QSC;
        bvv[et] = sm.bsh[64 + et*16 + L15];
    }

    half4 vown[2][2];       // own rows' V (for MLP input), avoids LDS round-trip
    #pragma unroll
    for (int mt = 0; mt < 2; mt++) {
        const float* p = x + ((size_t)b*N_ + qbase + w*32 + mt*16 + L15)*64 + g*32 + quad*8;
        half8 ax = cvt8(*(const float4*)p, *(const float4*)(p + 4));
        int rb = w*32 + mt*16 + quad*4;
        #pragma unroll
        for (int et = 0; et < 2; et++) {
            floatx4 cq = {bqv[et],bqv[et],bqv[et],bqv[et]};
            floatx4 cv = {bvv[et],bvv[et],bvv[et],bvv[et]};
            floatx4 dq = MFMA32(ax, bwq[et], cq, 0,0,0);
            floatx4 dk = MFMA32(ax, bwk[et], zz, 0,0,0);   // K bias dropped
            floatx4 dv = MFMA32(ax, bwv[et], cv, 0,0,0);
            #pragma unroll
            for (int r = 0; r < 4; r++)
                sm.u.p1.qs[(rb+r)*40 + et*16 + L15] = (_Float16)dq[r];
            half2 k01 = pkcvt(dk[0], dk[1]);
            half2 k23 = pkcvt(dk[2], dk[3]);
            sm.u.p1.kst[(rb+0)*32 + et*16 + L15] = k01[0];
            sm.u.p1.kst[(rb+1)*32 + et*16 + L15] = k01[1];
            sm.u.p1.kst[(rb+2)*32 + et*16 + L15] = k23[0];
            sm.u.p1.kst[(rb+3)*32 + et*16 + L15] = k23[1];
            half2 v01 = pkcvt(dv[0], dv[1]);
            half2 v23 = pkcvt(dv[2], dv[3]);
            half4 vh = { v01[0], v01[1], v23[0], v23[1] };
            *(half4*)&sm.u.p1.vt[(et*16 + L15)*136 + rb] = vh;
            vown[mt][et] = vh;
        }
    }
    __syncthreads();

    // Q B-frags (own 32 rows per wave)
    half8 bq0 = *(const half8*)&sm.u.p1.qs[(w*32 +      L15)*40 + quad*8];
    half8 bq1 = *(const half8*)&sm.u.p1.qs[(w*32 + 16 + L15)*40 + quad*8];

    // coalesced K out: [bg][n][e] f16
    {
        const float4* s4 = (const float4*)sm.u.p1.kst;
        float4* d4 = (float4*)(Kg + (size_t)bg*32768 + (size_t)qbase*32);
        d4[t] = s4[t];
        d4[t+256] = s4[t+256];
    }
    // coalesced Vt out: [bg][e][n] f16 — each thread copies 16 halves (2x float4)
    {
        int e = t >> 3, c = t & 7;
        const float4* s4 = (const float4*)&sm.u.p1.vt[e*136 + c*16];
        float4* d4 = (float4*)(Vtg + (size_t)bg*32768 + (size_t)e*1024 + qbase + c*16);
        d4[0] = s4[0];
        d4[1] = s4[1];
    }

    // -------- publish own slice: release fence + MAGIC flag --------
    __threadfence();       // agent-scope: ws stores visible device-wide
    __syncthreads();       // all threads fenced; all phase-1 LDS reads done
    if (t == 0)
        __hip_atomic_store(&flags[bg*8 + qtile], MAGIC,
                           __ATOMIC_RELEASE, __HIP_MEMORY_SCOPE_AGENT);

    // ================= Phase 2: attention over all 8 K-tiles =================
    const _Float16* kgB = Kg  + (size_t)bg*32768;
    const _Float16* vgB = Vtg + (size_t)bg*32768;
    const unsigned* fB = &flags[bg*8];
    auto wait_tile = [&](int tj) {
        for (int s_ = 0; s_ < (1<<20); ++s_) {
            if (__hip_atomic_load(&fB[tj], __ATOMIC_ACQUIRE,
                                  __HIP_MEMORY_SCOPE_AGENT) == MAGIC)
                break;
        }
    };
    // K staging: lane covers row l>>2 (of 16-row chunk), 16B-chunk (l&3)^((l>>3)&3)
    int kRow   = lane >> 2;
    int kChunk = (lane & 3) ^ ((lane >> 3) & 3);

    auto stage = [&](int tile, int bufi) {
        #pragma unroll
        for (int d = 0; d < 2; d++) {
            gload16(kgB + (size_t)(tile*128 + w*32 + d*16 + kRow)*32 + kChunk*8,
                    &sm.u.p2.K[bufi][w*1024 + d*512]);
            int e  = w*8 + d*4 + (lane >> 4);
            int vc = (lane & 15) ^ (e & 7);
            gload16(vgB + (size_t)e*1024 + tile*128 + vc*8,
                    &sm.u.p2.Vt[bufi][w*1024 + d*512]);
        }
    };

    floatx4 o00 = zz, o01 = zz, o10 = zz, o11 = zz;
    float lsum0 = 0.f, lsum1 = 0.f;
    int kswz = (quad ^ ((L15 >> 1) & 3)) * 8;
    int vswz = ((L15 & 7) << 1);

    wait_tile(0);
    stage(0, 0);
    __syncthreads();

    for (int kt = 0; kt < 8; kt++) {
        int cur = kt & 1;
        if (kt < 7) {
            wait_tile(kt + 1);
            stage(kt + 1, cur ^ 1);
        }
        __builtin_amdgcn_s_setprio(1);
        #pragma unroll
        for (int m8 = 0; m8 < 8; m8++) {
            half8 ak = *(const half8*)&sm.u.p2.K[cur][(m8*16 + L15)*32 + kswz];
            floatx4 s0 = MFMA32(ak, bq0, zz, 0,0,0);
            floatx4 s1 = MFMA32(ak, bq1, zz, 0,0,0);
            float p00 = EXP2(s0.x), p01 = EXP2(s0.y), p02 = EXP2(s0.z), p03 = EXP2(s0.w);
            float p10 = EXP2(s1.x), p11 = EXP2(s1.y), p12 = EXP2(s1.z), p13 = EXP2(s1.w);
            lsum0 += (p00+p01)+(p02+p03);
            lsum1 += (p10+p11)+(p12+p13);
            half2 pa = pkcvt(p00, p01);
            half2 pb = pkcvt(p02, p03);
            half2 pc = pkcvt(p10, p11);
            half2 pd = pkcvt(p12, p13);
            half4 a0 = { pa[0], pa[1], pb[0], pb[1] };
            half4 a1 = { pc[0], pc[1], pd[0], pd[1] };
            int vg_ = ((m8*4 + quad) ^ vswz) * 4;
            half4 bv0 = *(const half4*)&sm.u.p2.Vt[cur][      L15*128 + vg_];
            half4 bv1 = *(const half4*)&sm.u.p2.Vt[cur][(16 + L15)*128 + vg_];
            o00 = MFMA16(a0, bv0, o00, 0,0,0);
            o01 = MFMA16(a0, bv1, o01, 0,0,0);
            o10 = MFMA16(a1, bv0, o10, 0,0,0);
            o11 = MFMA16(a1, bv1, o11, 0,0,0);
        }
        __builtin_amdgcn_s_setprio(0);
        __syncthreads();
    }

    // ================= Phase 3: softmax denom + MLP =================
    lsum0 += __shfl_xor(lsum0, 16, 64); lsum0 += __shfl_xor(lsum0, 32, 64);
    lsum1 += __shfl_xor(lsum1, 16, 64); lsum1 += __shfl_xor(lsum1, 32, 64);
    float inv0 = 1.0f / lsum0;   // row w*32 + L15
    float inv1 = 1.0f / lsum1;   // row w*32 + 16 + L15
    float li[2][4];
    #pragma unroll
    for (int r = 0; r < 4; r++) {
        li[0][r] = __shfl(inv0, quad*4 + r, 64);
        li[1][r] = __shfl(inv1, quad*4 + r, 64);
    }

    // xs rows are wave-private: no barrier needed after the loop's final one
    {
        const floatx4* ofr[2][2] = { {&o00,&o01}, {&o10,&o11} };
        #pragma unroll
        for (int nt = 0; nt < 2; nt++) {
            int rb = w*32 + nt*16 + quad*4;
            #pragma unroll
            for (int et = 0; et < 2; et++) {
                #pragma unroll
                for (int r = 0; r < 4; r++)
                    sm.u.xs[(rb+r)*72 + et*16 + L15] = vown[nt][et][r];
                floatx4 ov = *ofr[nt][et];
                sm.u.xs[(rb+0)*72 + 32 + et*16 + L15] = (_Float16)(ov[0]*li[nt][0]);
                sm.u.xs[(rb+1)*72 + 32 + et*16 + L15] = (_Float16)(ov[1]*li[nt][1]);
                sm.u.xs[(rb+2)*72 + 32 + et*16 + L15] = (_Float16)(ov[2]*li[nt][2]);
                sm.u.xs[(rb+3)*72 + 32 + et*16 + L15] = (_Float16)(ov[3]*li[nt][3]);
            }
        }
    }

    // MLP weight A-frags
    half4 a1f[2][4], a2f[2][2], a3f[2][2];
    #pragma unroll
    for (int mt = 0; mt < 2; mt++) {
        #pragma unroll
        for (int kt = 0; kt < 4; kt++) {
            float4 f = *(const float4*)(w_h1 + (size_t)(g*32+mt*16+L15)*64 + kt*16 + quad*4);
            half2 ha = pkcvt(f.x, f.y);
            half2 hb = pkcvt(f.z, f.w);
            half4 h = { ha[0], ha[1], hb[0], hb[1] };
            a1f[mt][kt] = h;
        }
        #pragma unroll
        for (int kt = 0; kt < 2; kt++) {
            float4 f = *(const float4*)(w_h10 + (size_t)(g*32+mt*16+L15)*32 + kt*16 + quad*4);
            half2 ha = pkcvt(f.x, f.y);
            half2 hb = pkcvt(f.z, f.w);
            half4 h = { ha[0], ha[1], hb[0], hb[1] };
            a2f[mt][kt] = h;
            float4 f2 = *(const float4*)(w_h11 + (size_t)(g*32+mt*16+L15)*32 + kt*16 + quad*4);
            half2 hc = pkcvt(f2.x, f2.y);
            half2 hd = pkcvt(f2.z, f2.w);
            half4 h2 = { hc[0], hc[1], hd[0], hd[1] };
            a3f[mt][kt] = h2;
        }
    }

    floatx4 d1[2][2];
    #pragma unroll
    for (int mt = 0; mt < 2; mt++) {
        float4 bb = *(const float4*)&sm.bl1[mt*16 + quad*4];
        floatx4 seed = { bb.x, bb.y, bb.z, bb.w };
        d1[mt][0] = seed; d1[mt][1] = seed;
    }
    #pragma unroll
    for (int nt = 0; nt < 2; nt++)
        #pragma unroll
        for (int kt = 0; kt < 4; kt++) {
            half4 b1 = *(const half4*)&sm.u.xs[(w*32+nt*16+L15)*72 + kt*16 + quad*4];
            d1[0][nt] = MFMA16(a1f[0][kt], b1, d1[0][nt], 0,0,0);
            d1[1][nt] = MFMA16(a1f[1][kt], b1, d1[1][nt], 0,0,0);
        }
    half4 h1b[2][2];
    #pragma unroll
    for (int mt = 0; mt < 2; mt++)
        #pragma unroll
        for (int nt = 0; nt < 2; nt++) {
            float v0 = d1[mt][nt][0]; v0 = (v0>=0.f)?v0:NEG*v0;
            float v1 = d1[mt][nt][1]; v1 = (v1>=0.f)?v1:NEG*v1;
            float v2 = d1[mt][nt][2]; v2 = (v2>=0.f)?v2:NEG*v2;
            float v3 = d1[mt][nt][3]; v3 = (v3>=0.f)?v3:NEG*v3;
            half2 ha = pkcvt(v0, v1);
            half2 hb = pkcvt(v2, v3);
            half4 h = { ha[0], ha[1], hb[0], hb[1] };
            h1b[mt][nt] = h;
        }
    floatx4 d2[2][2];
    #pragma unroll
    for (int mt = 0; mt < 2; mt++) {
        float4 bb = *(const float4*)&sm.bl10[mt*16 + quad*4];
        floatx4 seed = { bb.x, bb.y, bb.z, bb.w };
        d2[mt][0] = seed; d2[mt][1] = seed;
    }
    #pragma unroll
    for (int mt = 0; mt < 2; mt++)
        #pragma unroll
        for (int nt = 0; nt < 2; nt++)
            #pragma unroll
            for (int kt = 0; kt < 2; kt++)
                d2[mt][nt] = MFMA16(a2f[mt][kt], h1b[kt][nt], d2[mt][nt], 0,0,0);
    half4 h2b[2][2];
    #pragma unroll
    for (int mt = 0; mt < 2; mt++)
        #pragma unroll
        for (int nt = 0; nt < 2; nt++) {
            float v0 = d2[mt][nt][0]; v0 = (v0>=0.f)?v0:NEG*v0;
            float v1 = d2[mt][nt][1]; v1 = (v1>=0.f)?v1:NEG*v1;
            float v2 = d2[mt][nt][2]; v2 = (v2>=0.f)?v2:NEG*v2;
            float v3 = d2[mt][nt][3]; v3 = (v3>=0.f)?v3:NEG*v3;
            half2 ha = pkcvt(v0, v1);
            half2 hb = pkcvt(v2, v3);
            half4 h = { ha[0], ha[1], hb[0], hb[1] };
            h2b[mt][nt] = h;
        }
    floatx4 d3[2][2];
    #pragma unroll
    for (int mt = 0; mt < 2; mt++) {
        float4 bb = *(const float4*)&sm.bl11[mt*16 + quad*4];
        floatx4 seed = { bb.x, bb.y, bb.z, bb.w };
        d3[mt][0] = seed; d3[mt][1] = seed;
    }
    #pragma unroll
    for (int mt = 0; mt < 2; mt++)
        #pragma unroll
        for (int nt = 0; nt < 2; nt++)
            #pragma unroll
            for (int kt = 0; kt < 2; kt++)
                d3[mt][nt] = MFMA16(a3f[mt][kt], h2b[kt][nt], d3[mt][nt], 0,0,0);
    #pragma unroll
    for (int mt = 0; mt < 2; mt++)
        #pragma unroll
        for (int nt = 0; nt < 2; nt++) {
            float4 ov;
            ov.x = d3[mt][nt][0]; ov.x = (ov.x>=0.f)?ov.x:NEG*ov.x;
            ov.y = d3[mt][nt][1]; ov.y = (ov.y>=0.f)?ov.y:NEG*ov.y;
            ov.z = d3[mt][nt][2]; ov.z = (ov.z>=0.f)?ov.z:NEG*ov.z;
            ov.w = d3[mt][nt][3]; ov.w = (ov.w>=0.f)?ov.w:NEG*ov.w;
            *(float4*)(out + ((size_t)b*N_ + qbase + w*32 + nt*16 + L15)*64 + g*32 + mt*16 + quad*4) = ov;
        }
}

extern "C" void kernel_launch(void* const* d_in, const int* in_sizes, int n_in,
                              void* d_out, int out_size, void* d_ws, size_t ws_size,
                              hipStream_t stream) {
    const float* x_e   = (const float*)d_in[0];
    const float* w_qkv = (const float*)d_in[1];
    const float* b_qkv = (const float*)d_in[2];
    const float* w_h1  = (const float*)d_in[3];
    const float* b_h1  = (const float*)d_in[4];
    const float* w_h10 = (const float*)d_in[5];
    const float* b_h10 = (const float*)d_in[6];
    const float* w_h11 = (const float*)d_in[7];
    const float* b_h11 = (const float*)d_in[8];
    float* out = (float*)d_out;

    _Float16* Kg   = (_Float16*)d_ws;                    // 4 MB
    _Float16* Vtg  = (_Float16*)d_ws + (1u<<21);         // 4 MB
    unsigned* flags = (unsigned*)((_Float16*)d_ws + (2u<<21));  // 512 words

    hipLaunchKernelGGL(fused_kernel, dim3(512), dim3(256), 0, stream,
                       x_e, w_qkv, b_qkv, w_h1, b_h1, w_h10, b_h10, w_h11, b_h11,
                       out, Kg, Vtg, flags);
}

// Round 8
// 111.059 us; speedup vs baseline: 2.4717x; 2.4717x over previous
//
#include <hip/hip_runtime.h>

#define B_ 32
#define N_ 1024
#define NEG 0.01f
#define QSC (1.4426950408889634f/32.0f)   // log2(e)/E folded into staged Wq/bq

using half8  = __attribute__((ext_vector_type(8))) _Float16;
using half4  = __attribute__((ext_vector_type(4))) _Float16;
using half2  = __attribute__((ext_vector_type(2))) _Float16;
using fp16x2 = __attribute__((ext_vector_type(2))) __fp16;
using floatx4 = __attribute__((ext_vector_type(4))) float;

#if defined(__has_builtin)
#if __has_builtin(__builtin_amdgcn_exp2f)
#define EXP2(x) __builtin_amdgcn_exp2f(x)
#endif
#endif
#ifndef EXP2
#define EXP2(x) exp2f(x)
#endif

#define MFMA32 __builtin_amdgcn_mfma_f32_16x16x32_f16
#define MFMA16 __builtin_amdgcn_mfma_f32_16x16x16f16

__device__ inline half2 pkcvt(float a, float b) {
    fp16x2 r = __builtin_amdgcn_cvt_pkrtz(a, b);
    return __builtin_bit_cast(half2, r);
}

__device__ inline half8 cvt8(float4 a, float4 b) {
    half2 p0 = pkcvt(a.x, a.y);
    half2 p1 = pkcvt(a.z, a.w);
    half2 p2 = pkcvt(b.x, b.y);
    half2 p3 = pkcvt(b.z, b.w);
    half8 h = { p0[0],p0[1], p1[0],p1[1], p2[0],p2[1], p3[0],p3[1] };
    return h;
}

// Round-4 structure (4 waves x 32 q-rows, in-block K/V projection, known-good)
// with LDS squeezed 62.5 -> 42.5 KB so 3 blocks/CU fit (12 waves/CU vs 8):
//  - Kst stride 40->36 (K-frag read becomes uniform 2-way: free)
//  - qs aliased onto Kst[1] (bq frags read before Kst[1]'s first write)
//  - xs unions with Kst[0..1]; post-loop barrier protects the alias
//  - own-V in regs (vown), K bias dropped (softmax shift-invariant)
// launch_bounds(256,3): VGPR cap ~168 (demand est ~150; spills show in WRITE_SIZE)
struct __align__(16) Smem {
    _Float16 wsh[96*36];       // 6912B: Wq(pre-scaled)/Wk/Wv, stride 36
    float    bsh[96];          // 384B
    union {
        struct {
            _Float16 Kst[2][128*36];   // ping-pong K tile [kpos][e]; Kst[1] = qs pre-loop
            _Float16 Vtst[2][32*136];  // ping-pong Vt tile [e][kpos]
        } a;
        _Float16 xs[128*72];           // epilogue MLP input [q][ v(32) | attn(32) ]
    } u;
    float bl1[32], bl10[32], bl11[32];
};  // 43520 B -> 3 blocks/CU (LDS-limited: 3*42.5 = 127.5KB <= 160KB)

__global__ __launch_bounds__(256, 3) void fused_kernel(
    const float* __restrict__ x, const float* __restrict__ w_qkv, const float* __restrict__ b_qkv,
    const float* __restrict__ w_h1,  const float* __restrict__ b_h1,
    const float* __restrict__ w_h10, const float* __restrict__ b_h10,
    const float* __restrict__ w_h11, const float* __restrict__ b_h11,
    float* __restrict__ out)
{
    __shared__ Smem sm;
    int t = threadIdx.x;
    int bid = blockIdx.x;
    // XCD-affine remap: all 8 q-tile blocks of one bg land on the same XCD
    int xcd = bid & 7, j = bid >> 3;
    int bg = xcd*8 + (j >> 3);
    int qtile = j & 7;
    int b = bg >> 1, g = bg & 1;
    int qbase = qtile * 128;
    int lane = t & 63, w = t >> 6;
    int L15 = lane & 15, quad = lane >> 4;
    const floatx4 zz = {0.f,0.f,0.f,0.f};

    // ---- stage qkv weights (Q rows pre-scaled by QSC) + biases ----
    for (int idx = t; idx < 96*32; idx += 256) {
        int r = idx >> 5, c = idx & 31;
        float wv = w_qkv[(g*96 + r)*32 + c];
        sm.wsh[r*36 + c] = (_Float16)(r < 32 ? wv*QSC : wv);
    }
    if (t < 96) sm.bsh[t] = b_qkv[g*96 + t];
    if (t < 32) {
        sm.bl1[t]  = b_h1[g*32+t];
        sm.bl10[t] = b_h10[g*32+t];
        sm.bl11[t] = b_h11[g*32+t];
    }
    __syncthreads();

    // ---- weight B-frags + bias seeds (K bias dropped: shift-invariant) ----
    half8 bwq[2], bwk[2], bwv[2];
    floatx4 cv[2];
    #pragma unroll
    for (int et = 0; et < 2; et++) {
        bwq[et] = *(const half8*)&sm.wsh[(     et*16 + L15)*36 + quad*8];
        bwk[et] = *(const half8*)&sm.wsh[(32 + et*16 + L15)*36 + quad*8];
        bwv[et] = *(const half8*)&sm.wsh[(64 + et*16 + L15)*36 + quad*8];
        float bv = sm.bsh[64 + et*16 + L15];
        cv[et] = (floatx4){bv,bv,bv,bv};
    }

    _Float16* qs = sm.u.a.Kst[1];   // alias: dead once bq frags are read

    // ---- project Q for own 32 rows/wave -> qs (stride 36) ----
    #pragma unroll
    for (int mt = 0; mt < 2; mt++) {
        const float* p = x + ((size_t)b*N_ + qbase + w*32 + mt*16 + L15)*64 + g*32 + quad*8;
        half8 axq = cvt8(*(const float4*)p, *(const float4*)(p + 4));
        #pragma unroll
        for (int et = 0; et < 2; et++) {
            float bq = sm.bsh[et*16 + L15] * QSC;
            floatx4 cq = {bq,bq,bq,bq};
            floatx4 dq = MFMA32(axq, bwq[et], cq, 0,0,0);
            #pragma unroll
            for (int r = 0; r < 4; r++)
                qs[(w*32 + mt*16 + quad*4 + r)*36 + et*16 + L15] = (_Float16)dq[r];
        }
    }
    __syncthreads();
    half8 bq0 = *(const half8*)&qs[(w*32 +      L15)*36 + quad*8];
    half8 bq1 = *(const half8*)&qs[(w*32 + 16 + L15)*36 + quad*8];
    // Kst[1] is first written by proj_tile(1,1) inside loop iter 0, which is
    // after the prologue barrier below -> all bq reads complete before then.

    half4 vown[2][2];   // own rows' V for the MLP input (no LDS round-trip)
    float4 xf0[2], xf1[2];
    auto prefetch = [&](int tile) {
        #pragma unroll
        for (int mt = 0; mt < 2; mt++) {
            const float* p = x + ((size_t)b*N_ + tile*128 + w*32 + mt*16 + L15)*64 + g*32 + quad*8;
            xf0[mt] = *(const float4*)p;
            xf1[mt] = *(const float4*)(p + 4);
        }
    };
    auto proj_tile = [&](int tile, int buf) {
        floatx4 dK[2][2], dV[2][2];
        #pragma unroll
        for (int mt = 0; mt < 2; mt++) {
            half8 axk = cvt8(xf0[mt], xf1[mt]);
            dK[mt][0] = MFMA32(axk, bwk[0], zz, 0,0,0);
            dK[mt][1] = MFMA32(axk, bwk[1], zz, 0,0,0);
            dV[mt][0] = MFMA32(axk, bwv[0], cv[0], 0,0,0);
            dV[mt][1] = MFMA32(axk, bwv[1], cv[1], 0,0,0);
        }
        #pragma unroll
        for (int mt = 0; mt < 2; mt++) {
            int rb = w*32 + mt*16 + quad*4;
            #pragma unroll
            for (int et = 0; et < 2; et++) {
                half2 k01 = pkcvt(dK[mt][et][0], dK[mt][et][1]);
                half2 k23 = pkcvt(dK[mt][et][2], dK[mt][et][3]);
                half2 v01 = pkcvt(dV[mt][et][0], dV[mt][et][1]);
                half2 v23 = pkcvt(dV[mt][et][2], dV[mt][et][3]);
                half4 vh = { v01[0], v01[1], v23[0], v23[1] };
                sm.u.a.Kst[buf][(rb+0)*36 + et*16 + L15] = k01[0];
                sm.u.a.Kst[buf][(rb+1)*36 + et*16 + L15] = k01[1];
                sm.u.a.Kst[buf][(rb+2)*36 + et*16 + L15] = k23[0];
                sm.u.a.Kst[buf][(rb+3)*36 + et*16 + L15] = k23[1];
                *(half4*)&sm.u.a.Vtst[buf][(et*16 + L15)*136 + rb] = vh;
                if (tile == qtile) vown[mt][et] = vh;   // uniform branch
            }
        }
    };

    // ---- prologue: tile 0 ----
    prefetch(0);
    proj_tile(0, 0);
    __syncthreads();

    floatx4 o00 = zz, o01 = zz, o10 = zz, o11 = zz;
    float lsum0 = 0.f, lsum1 = 0.f;

    for (int kt = 0; kt < 8; kt++) {
        int cur = kt & 1;
        if (kt < 7) prefetch(kt + 1);
        __builtin_amdgcn_s_setprio(1);
        #pragma unroll
        for (int m8 = 0; m8 < 8; m8++) {
            half8 ak = *(const half8*)&sm.u.a.Kst[cur][(m8*16 + L15)*36 + quad*8];
            floatx4 s0 = MFMA32(ak, bq0, zz, 0,0,0);
            floatx4 s1 = MFMA32(ak, bq1, zz, 0,0,0);
            float p00 = EXP2(s0.x), p01 = EXP2(s0.y), p02 = EXP2(s0.z), p03 = EXP2(s0.w);
            float p10 = EXP2(s1.x), p11 = EXP2(s1.y), p12 = EXP2(s1.z), p13 = EXP2(s1.w);
            lsum0 += (p00+p01)+(p02+p03);
            lsum1 += (p10+p11)+(p12+p13);
            half2 pa = pkcvt(p00, p01);
            half2 pb = pkcvt(p02, p03);
            half2 pc = pkcvt(p10, p11);
            half2 pd = pkcvt(p12, p13);
            half4 a0 = { pa[0], pa[1], pb[0], pb[1] };
            half4 a1 = { pc[0], pc[1], pd[0], pd[1] };
            half4 bv0 = *(const half4*)&sm.u.a.Vtst[cur][      L15*136 + m8*16 + quad*4];
            half4 bv1 = *(const half4*)&sm.u.a.Vtst[cur][(16 + L15)*136 + m8*16 + quad*4];
            o00 = MFMA16(a0, bv0, o00, 0,0,0);
            o01 = MFMA16(a0, bv1, o01, 0,0,0);
            o10 = MFMA16(a1, bv0, o10, 0,0,0);
            o11 = MFMA16(a1, bv1, o11, 0,0,0);
        }
        __builtin_amdgcn_s_setprio(0);
        if (kt < 7) {
            proj_tile(kt + 1, 1 - cur);
            __syncthreads();
        }
    }
    __syncthreads();   // all waves done reading Kst/Vtst before xs (alias) writes

    // ---- softmax denominators: fold quads, per-row inverses via shuffles ----
    lsum0 += __shfl_xor(lsum0, 16, 64); lsum0 += __shfl_xor(lsum0, 32, 64);
    lsum1 += __shfl_xor(lsum1, 16, 64); lsum1 += __shfl_xor(lsum1, 32, 64);
    float inv0 = 1.0f / lsum0;   // row w*32 + L15 (all lanes)
    float inv1 = 1.0f / lsum1;   // row w*32 + 16 + L15
    float li[2][4];
    #pragma unroll
    for (int r = 0; r < 4; r++) {
        li[0][r] = __shfl(inv0, quad*4 + r, 64);
        li[1][r] = __shfl(inv1, quad*4 + r, 64);
    }

    // ---- xs: v-part from vown regs, attn-part from O regs (rows wave-private) ----
    {
        const floatx4* ofr[2][2] = { {&o00,&o01}, {&o10,&o11} };
        #pragma unroll
        for (int nt = 0; nt < 2; nt++) {
            int rb = w*32 + nt*16 + quad*4;
            #pragma unroll
            for (int et = 0; et < 2; et++) {
                #pragma unroll
                for (int r = 0; r < 4; r++)
                    sm.u.xs[(rb+r)*72 + et*16 + L15] = vown[nt][et][r];
                floatx4 ov = *ofr[nt][et];
                sm.u.xs[(rb+0)*72 + 32 + et*16 + L15] = (_Float16)(ov[0]*li[nt][0]);
                sm.u.xs[(rb+1)*72 + 32 + et*16 + L15] = (_Float16)(ov[1]*li[nt][1]);
                sm.u.xs[(rb+2)*72 + 32 + et*16 + L15] = (_Float16)(ov[2]*li[nt][2]);
                sm.u.xs[(rb+3)*72 + 32 + et*16 + L15] = (_Float16)(ov[3]*li[nt][3]);
            }
        }
    }

    // ---- MLP weight A-frags: A[m=o=mt*16+L15][k=i=quad*4+j] ----
    half4 a1f[2][4], a2f[2][2], a3f[2][2];
    #pragma unroll
    for (int mt = 0; mt < 2; mt++) {
        #pragma unroll
        for (int kt = 0; kt < 4; kt++) {
            float4 f = *(const float4*)(w_h1 + (size_t)(g*32+mt*16+L15)*64 + kt*16 + quad*4);
            half2 ha = pkcvt(f.x, f.y);
            half2 hb = pkcvt(f.z, f.w);
            half4 h = { ha[0], ha[1], hb[0], hb[1] };
            a1f[mt][kt] = h;
        }
        #pragma unroll
        for (int kt = 0; kt < 2; kt++) {
            float4 f = *(const float4*)(w_h10 + (size_t)(g*32+mt*16+L15)*32 + kt*16 + quad*4);
            half2 ha = pkcvt(f.x, f.y);
            half2 hb = pkcvt(f.z, f.w);
            half4 h = { ha[0], ha[1], hb[0], hb[1] };
            a2f[mt][kt] = h;
            float4 f2 = *(const float4*)(w_h11 + (size_t)(g*32+mt*16+L15)*32 + kt*16 + quad*4);
            half2 hc = pkcvt(f2.x, f2.y);
            half2 hd = pkcvt(f2.z, f2.w);
            half4 h2 = { hc[0], hc[1], hd[0], hd[1] };
            a3f[mt][kt] = h2;
        }
    }

    // ---- layer 1 (bias-seeded): D[o][q] over this wave's 32 q rows ----
    floatx4 d1[2][2];
    #pragma unroll
    for (int mt = 0; mt < 2; mt++) {
        float4 bb = *(const float4*)&sm.bl1[mt*16 + quad*4];
        floatx4 seed = { bb.x, bb.y, bb.z, bb.w };
        d1[mt][0] = seed; d1[mt][1] = seed;
    }
    #pragma unroll
    for (int nt = 0; nt < 2; nt++)
        #pragma unroll
        for (int kt = 0; kt < 4; kt++) {
            half4 b1 = *(const half4*)&sm.u.xs[(w*32+nt*16+L15)*72 + kt*16 + quad*4];
            d1[0][nt] = MFMA16(a1f[0][kt], b1, d1[0][nt], 0,0,0);
            d1[1][nt] = MFMA16(a1f[1][kt], b1, d1[1][nt], 0,0,0);
        }
    half4 h1b[2][2];   // C layout == next layer's B layout: in-register chain
    #pragma unroll
    for (int mt = 0; mt < 2; mt++)
        #pragma unroll
        for (int nt = 0; nt < 2; nt++) {
            float v0 = d1[mt][nt][0]; v0 = (v0>=0.f)?v0:NEG*v0;
            float v1 = d1[mt][nt][1]; v1 = (v1>=0.f)?v1:NEG*v1;
            float v2 = d1[mt][nt][2]; v2 = (v2>=0.f)?v2:NEG*v2;
            float v3 = d1[mt][nt][3]; v3 = (v3>=0.f)?v3:NEG*v3;
            half2 ha = pkcvt(v0, v1);
            half2 hb = pkcvt(v2, v3);
            half4 h = { ha[0], ha[1], hb[0], hb[1] };
            h1b[mt][nt] = h;
        }
    floatx4 d2[2][2];
    #pragma unroll
    for (int mt = 0; mt < 2; mt++) {
        float4 bb = *(const float4*)&sm.bl10[mt*16 + quad*4];
        floatx4 seed = { bb.x, bb.y, bb.z, bb.w };
        d2[mt][0] = seed; d2[mt][1] = seed;
    }
    #pragma unroll
    for (int mt = 0; mt < 2; mt++)
        #pragma unroll
        for (int nt = 0; nt < 2; nt++)
            #pragma unroll
            for (int kt = 0; kt < 2; kt++)
                d2[mt][nt] = MFMA16(a2f[mt][kt], h1b[kt][nt], d2[mt][nt], 0,0,0);
    half4 h2b[2][2];
    #pragma unroll
    for (int mt = 0; mt < 2; mt++)
        #pragma unroll
        for (int nt = 0; nt < 2; nt++) {
            float v0 = d2[mt][nt][0]; v0 = (v0>=0.f)?v0:NEG*v0;
            float v1 = d2[mt][nt][1]; v1 = (v1>=0.f)?v1:NEG*v1;
            float v2 = d2[mt][nt][2]; v2 = (v2>=0.f)?v2:NEG*v2;
            float v3 = d2[mt][nt][3]; v3 = (v3>=0.f)?v3:NEG*v3;
            half2 ha = pkcvt(v0, v1);
            half2 hb = pkcvt(v2, v3);
            half4 h = { ha[0], ha[1], hb[0], hb[1] };
            h2b[mt][nt] = h;
        }
    floatx4 d3[2][2];
    #pragma unroll
    for (int mt = 0; mt < 2; mt++) {
        float4 bb = *(const float4*)&sm.bl11[mt*16 + quad*4];
        floatx4 seed = { bb.x, bb.y, bb.z, bb.w };
        d3[mt][0] = seed; d3[mt][1] = seed;
    }
    #pragma unroll
    for (int mt = 0; mt < 2; mt++)
        #pragma unroll
        for (int nt = 0; nt < 2; nt++)
            #pragma unroll
            for (int kt = 0; kt < 2; kt++)
                d3[mt][nt] = MFMA16(a3f[mt][kt], h2b[kt][nt], d3[mt][nt], 0,0,0);
    // store: lane holds out[q=qbase+w*32+nt*16+L15][o=mt*16+quad*4+r] -> float4
    #pragma unroll
    for (int mt = 0; mt < 2; mt++)
        #pragma unroll
        for (int nt = 0; nt < 2; nt++) {
            float4 ov;
            ov.x = d3[mt][nt][0]; ov.x = (ov.x>=0.f)?ov.x:NEG*ov.x;
            ov.y = d3[mt][nt][1]; ov.y = (ov.y>=0.f)?ov.y:NEG*ov.y;
            ov.z = d3[mt][nt][2]; ov.z = (ov.z>=0.f)?ov.z:NEG*ov.z;
            ov.w = d3[mt][nt][3]; ov.w = (ov.w>=0.f)?ov.w:NEG*ov.w;
            *(float4*)(out + ((size_t)b*N_ + qbase + w*32 + nt*16 + L15)*64 + g*32 + mt*16 + quad*4) = ov;
        }
}

extern "C" void kernel_launch(void* const* d_in, const int* in_sizes, int n_in,
                              void* d_out, int out_size, void* d_ws, size_t ws_size,
                              hipStream_t stream) {
    const float* x_e   = (const float*)d_in[0];
    const float* w_qkv = (const float*)d_in[1];
    const float* b_qkv = (const float*)d_in[2];
    const float* w_h1  = (const float*)d_in[3];
    const float* b_h1  = (const float*)d_in[4];
    const float* w_h10 = (const float*)d_in[5];
    const float* b_h10 = (const float*)d_in[6];
    const float* w_h11 = (const float*)d_in[7];
    const float* b_h11 = (const float*)d_in[8];
    float* out = (float*)d_out;

    hipLaunchKernelGGL(fused_kernel, dim3(B_*2*8), dim3(256), 0, stream,
                       x_e, w_qkv, b_qkv, w_h1, b_h1, w_h10, b_h10, w_h11, b_h11, out);
}

// Round 9
// 97.848 us; speedup vs baseline: 2.8054x; 1.1350x over previous
//
#include <hip/hip_runtime.h>

#define B_ 32
#define N_ 1024
#define NEG 0.01f
#define QSC (1.4426950408889634f/32.0f)   // log2(e)/E folded into staged Wq/bq

using half8  = __attribute__((ext_vector_type(8))) _Float16;
using half4  = __attribute__((ext_vector_type(4))) _Float16;
using half2  = __attribute__((ext_vector_type(2))) _Float16;
using fp16x2 = __attribute__((ext_vector_type(2))) __fp16;
using floatx4 = __attribute__((ext_vector_type(4))) float;

#if defined(__has_builtin)
#if __has_builtin(__builtin_amdgcn_exp2f)
#define EXP2(x) __builtin_amdgcn_exp2f(x)
#endif
#endif
#ifndef EXP2
#define EXP2(x) exp2f(x)
#endif

#define MFMA32 __builtin_amdgcn_mfma_f32_16x16x32_f16
#define MFMA16 __builtin_amdgcn_mfma_f32_16x16x16f16

__device__ inline half2 pkcvt(float a, float b) {
    fp16x2 r = __builtin_amdgcn_cvt_pkrtz(a, b);
    return __builtin_bit_cast(half2, r);
}

__device__ inline half8 cvt8(float4 a, float4 b) {
    half2 p0 = pkcvt(a.x, a.y);
    half2 p1 = pkcvt(a.z, a.w);
    half2 p2 = pkcvt(b.x, b.y);
    half2 p3 = pkcvt(b.z, b.w);
    half8 h = { p0[0],p0[1], p1[0],p1[1], p2[0],p2[1], p3[0],p3[1] };
    return h;
}

// 4 waves x 32 q-rows; 43.5KB LDS -> 3 blocks/CU (12 waves/CU).
// launch_bounds(256,2): VGPR cap 128 (empirical cap = 256/min_waves:
// (256,3) -> 84 caused 13.6MB scratch spill in the previous round).
// Register-pressure cuts so demand < 128:
//  - proj_tile interleaved per-(mt,et): compute->pack->store (transient 64->16)
//  - k-loop STARTS AT qtile (softmax sum order-invariant): Q projected in the
//    same pass as tile qtile's K/V -> no separate Q pass, bwq dies early,
//    no tile==qtile branch in loop.
//  - qs aliased onto Kst[1] (bq frags read in-wave before the prologue
//    barrier; Kst[1] first written after it); xs unions with Kst; vown in regs.
struct __align__(16) Smem {
    _Float16 wsh[96*36];       // 6912B: Wq(pre-scaled)/Wk/Wv, stride 36
    float    bsh[96];          // 384B
    union {
        struct {
            _Float16 Kst[2][128*36];   // ping-pong K tile [kpos][e]; Kst[1]=qs pre-loop
            _Float16 Vtst[2][32*136];  // ping-pong Vt tile [e][kpos]
        } a;
        _Float16 xs[128*72];           // epilogue MLP input [q][ v(32) | attn(32) ]
    } u;
    float bl1[32], bl10[32], bl11[32];
};  // 43520 B

__global__ __launch_bounds__(256, 2) void fused_kernel(
    const float* __restrict__ x, const float* __restrict__ w_qkv, const float* __restrict__ b_qkv,
    const float* __restrict__ w_h1,  const float* __restrict__ b_h1,
    const float* __restrict__ w_h10, const float* __restrict__ b_h10,
    const float* __restrict__ w_h11, const float* __restrict__ b_h11,
    float* __restrict__ out)
{
    __shared__ Smem sm;
    int t = threadIdx.x;
    int bid = blockIdx.x;
    // XCD-affine remap: all 8 q-tile blocks of one bg land on the same XCD
    int xcd = bid & 7, j = bid >> 3;
    int bg = xcd*8 + (j >> 3);
    int qtile = j & 7;
    int b = bg >> 1, g = bg & 1;
    int qbase = qtile * 128;
    int lane = t & 63, w = t >> 6;
    int L15 = lane & 15, quad = lane >> 4;
    const floatx4 zz = {0.f,0.f,0.f,0.f};

    // ---- stage qkv weights (Q rows pre-scaled by QSC) + biases ----
    for (int idx = t; idx < 96*32; idx += 256) {
        int r = idx >> 5, c = idx & 31;
        float wv = w_qkv[(g*96 + r)*32 + c];
        sm.wsh[r*36 + c] = (_Float16)(r < 32 ? wv*QSC : wv);
    }
    if (t < 96) sm.bsh[t] = b_qkv[g*96 + t];
    if (t < 32) {
        sm.bl1[t]  = b_h1[g*32+t];
        sm.bl10[t] = b_h10[g*32+t];
        sm.bl11[t] = b_h11[g*32+t];
    }
    __syncthreads();

    // ---- weight B-frags + bias seeds (K bias dropped: shift-invariant) ----
    half8 bwq[2], bwk[2], bwv[2];
    floatx4 cv[2];
    #pragma unroll
    for (int et = 0; et < 2; et++) {
        bwq[et] = *(const half8*)&sm.wsh[(     et*16 + L15)*36 + quad*8];
        bwk[et] = *(const half8*)&sm.wsh[(32 + et*16 + L15)*36 + quad*8];
        bwv[et] = *(const half8*)&sm.wsh[(64 + et*16 + L15)*36 + quad*8];
        float bv = sm.bsh[64 + et*16 + L15];
        cv[et] = (floatx4){bv,bv,bv,bv};
    }

    _Float16* qs = sm.u.a.Kst[1];   // alias: dead once bq frags are read

    half4 vown[2][2];   // own rows' V for the MLP input (no LDS round-trip)
    float4 xf0[2], xf1[2];
    auto prefetch = [&](int tile) {
        #pragma unroll
        for (int mt = 0; mt < 2; mt++) {
            const float* p = x + ((size_t)b*N_ + tile*128 + w*32 + mt*16 + L15)*64 + g*32 + quad*8;
            xf0[mt] = *(const float4*)p;
            xf1[mt] = *(const float4*)(p + 4);
        }
    };
    // K/V projection of the prefetched tile; interleaved per-(mt,et) to keep
    // transient register pressure low (compute 2 MFMAs -> pack -> store).
    auto proj_tile = [&](int buf) {
        #pragma unroll
        for (int mt = 0; mt < 2; mt++) {
            half8 ax = cvt8(xf0[mt], xf1[mt]);
            int rb = w*32 + mt*16 + quad*4;
            #pragma unroll
            for (int et = 0; et < 2; et++) {
                floatx4 dk = MFMA32(ax, bwk[et], zz, 0,0,0);
                floatx4 dv = MFMA32(ax, bwv[et], cv[et], 0,0,0);
                half2 k01 = pkcvt(dk[0], dk[1]);
                half2 k23 = pkcvt(dk[2], dk[3]);
                sm.u.a.Kst[buf][(rb+0)*36 + et*16 + L15] = k01[0];
                sm.u.a.Kst[buf][(rb+1)*36 + et*16 + L15] = k01[1];
                sm.u.a.Kst[buf][(rb+2)*36 + et*16 + L15] = k23[0];
                sm.u.a.Kst[buf][(rb+3)*36 + et*16 + L15] = k23[1];
                half2 v01 = pkcvt(dv[0], dv[1]);
                half2 v23 = pkcvt(dv[2], dv[3]);
                half4 vh = { v01[0], v01[1], v23[0], v23[1] };
                *(half4*)&sm.u.a.Vtst[buf][(et*16 + L15)*136 + rb] = vh;
            }
        }
    };

    // ---- prologue: tile qtile -> Q (qs + vown) and K/V (buf 0) in ONE pass ----
    prefetch(qtile);
    #pragma unroll
    for (int mt = 0; mt < 2; mt++) {
        half8 ax = cvt8(xf0[mt], xf1[mt]);
        int rb = w*32 + mt*16 + quad*4;
        #pragma unroll
        for (int et = 0; et < 2; et++) {
            float bq = sm.bsh[et*16 + L15] * QSC;
            floatx4 cq = {bq,bq,bq,bq};
            floatx4 dq = MFMA32(ax, bwq[et], cq, 0,0,0);
            floatx4 dk = MFMA32(ax, bwk[et], zz, 0,0,0);
            floatx4 dv = MFMA32(ax, bwv[et], cv[et], 0,0,0);
            #pragma unroll
            for (int r = 0; r < 4; r++)
                qs[(rb+r)*36 + et*16 + L15] = (_Float16)dq[r];
            half2 k01 = pkcvt(dk[0], dk[1]);
            half2 k23 = pkcvt(dk[2], dk[3]);
            sm.u.a.Kst[0][(rb+0)*36 + et*16 + L15] = k01[0];
            sm.u.a.Kst[0][(rb+1)*36 + et*16 + L15] = k01[1];
            sm.u.a.Kst[0][(rb+2)*36 + et*16 + L15] = k23[0];
            sm.u.a.Kst[0][(rb+3)*36 + et*16 + L15] = k23[1];
            half2 v01 = pkcvt(dv[0], dv[1]);
            half2 v23 = pkcvt(dv[2], dv[3]);
            half4 vh = { v01[0], v01[1], v23[0], v23[1] };
            *(half4*)&sm.u.a.Vtst[0][(et*16 + L15)*136 + rb] = vh;
            vown[mt][et] = vh;
        }
    }
    // bq frags: wave w reads ONLY rows w*32..w*32+31, which wave w itself just
    // wrote -> in-wave DS ordering makes this safe BEFORE the barrier (and the
    // barrier's lgkmcnt(0) drains the reads before any wave can write Kst[1]).
    half8 bq0 = *(const half8*)&qs[(w*32 +      L15)*36 + quad*8];
    half8 bq1 = *(const half8*)&qs[(w*32 + 16 + L15)*36 + quad*8];
    __syncthreads();

    floatx4 o00 = zz, o01 = zz, o10 = zz, o11 = zz;
    float lsum0 = 0.f, lsum1 = 0.f;

    // ---- k-loop, physically starting at qtile (softmax sum order-invariant) ----
    for (int kt = 0; kt < 8; kt++) {
        int cur = kt & 1;
        if (kt < 7) prefetch((qtile + kt + 1) & 7);
        __builtin_amdgcn_s_setprio(1);
        #pragma unroll
        for (int m8 = 0; m8 < 8; m8++) {
            half8 ak = *(const half8*)&sm.u.a.Kst[cur][(m8*16 + L15)*36 + quad*8];
            floatx4 s0 = MFMA32(ak, bq0, zz, 0,0,0);
            floatx4 s1 = MFMA32(ak, bq1, zz, 0,0,0);
            float p00 = EXP2(s0.x), p01 = EXP2(s0.y), p02 = EXP2(s0.z), p03 = EXP2(s0.w);
            float p10 = EXP2(s1.x), p11 = EXP2(s1.y), p12 = EXP2(s1.z), p13 = EXP2(s1.w);
            lsum0 += (p00+p01)+(p02+p03);
            lsum1 += (p10+p11)+(p12+p13);
            half2 pa = pkcvt(p00, p01);
            half2 pb = pkcvt(p02, p03);
            half2 pc = pkcvt(p10, p11);
            half2 pd = pkcvt(p12, p13);
            half4 a0 = { pa[0], pa[1], pb[0], pb[1] };
            half4 a1 = { pc[0], pc[1], pd[0], pd[1] };
            half4 bv0 = *(const half4*)&sm.u.a.Vtst[cur][      L15*136 + m8*16 + quad*4];
            half4 bv1 = *(const half4*)&sm.u.a.Vtst[cur][(16 + L15)*136 + m8*16 + quad*4];
            o00 = MFMA16(a0, bv0, o00, 0,0,0);
            o01 = MFMA16(a0, bv1, o01, 0,0,0);
            o10 = MFMA16(a1, bv0, o10, 0,0,0);
            o11 = MFMA16(a1, bv1, o11, 0,0,0);
        }
        __builtin_amdgcn_s_setprio(0);
        if (kt < 7) {
            proj_tile(1 - cur);
            __syncthreads();
        }
    }
    __syncthreads();   // all waves done reading Kst/Vtst before xs (alias) writes

    // ---- softmax denominators: fold quads, per-row inverses via shuffles ----
    lsum0 += __shfl_xor(lsum0, 16, 64); lsum0 += __shfl_xor(lsum0, 32, 64);
    lsum1 += __shfl_xor(lsum1, 16, 64); lsum1 += __shfl_xor(lsum1, 32, 64);
    float inv0 = 1.0f / lsum0;   // row w*32 + L15 (all lanes)
    float inv1 = 1.0f / lsum1;   // row w*32 + 16 + L15
    float li[2][4];
    #pragma unroll
    for (int r = 0; r < 4; r++) {
        li[0][r] = __shfl(inv0, quad*4 + r, 64);
        li[1][r] = __shfl(inv1, quad*4 + r, 64);
    }

    // ---- xs: v-part from vown regs, attn-part from O regs (rows wave-private) ----
    {
        const floatx4* ofr[2][2] = { {&o00,&o01}, {&o10,&o11} };
        #pragma unroll
        for (int nt = 0; nt < 2; nt++) {
            int rb = w*32 + nt*16 + quad*4;
            #pragma unroll
            for (int et = 0; et < 2; et++) {
                #pragma unroll
                for (int r = 0; r < 4; r++)
                    sm.u.xs[(rb+r)*72 + et*16 + L15] = vown[nt][et][r];
                floatx4 ov = *ofr[nt][et];
                sm.u.xs[(rb+0)*72 + 32 + et*16 + L15] = (_Float16)(ov[0]*li[nt][0]);
                sm.u.xs[(rb+1)*72 + 32 + et*16 + L15] = (_Float16)(ov[1]*li[nt][1]);
                sm.u.xs[(rb+2)*72 + 32 + et*16 + L15] = (_Float16)(ov[2]*li[nt][2]);
                sm.u.xs[(rb+3)*72 + 32 + et*16 + L15] = (_Float16)(ov[3]*li[nt][3]);
            }
        }
    }

    // ---- MLP weight A-frags: A[m=o=mt*16+L15][k=i=quad*4+j] ----
    half4 a1f[2][4], a2f[2][2], a3f[2][2];
    #pragma unroll
    for (int mt = 0; mt < 2; mt++) {
        #pragma unroll
        for (int kt = 0; kt < 4; kt++) {
            float4 f = *(const float4*)(w_h1 + (size_t)(g*32+mt*16+L15)*64 + kt*16 + quad*4);
            half2 ha = pkcvt(f.x, f.y);
            half2 hb = pkcvt(f.z, f.w);
            half4 h = { ha[0], ha[1], hb[0], hb[1] };
            a1f[mt][kt] = h;
        }
        #pragma unroll
        for (int kt = 0; kt < 2; kt++) {
            float4 f = *(const float4*)(w_h10 + (size_t)(g*32+mt*16+L15)*32 + kt*16 + quad*4);
            half2 ha = pkcvt(f.x, f.y);
            half2 hb = pkcvt(f.z, f.w);
            half4 h = { ha[0], ha[1], hb[0], hb[1] };
            a2f[mt][kt] = h;
            float4 f2 = *(const float4*)(w_h11 + (size_t)(g*32+mt*16+L15)*32 + kt*16 + quad*4);
            half2 hc = pkcvt(f2.x, f2.y);
            half2 hd = pkcvt(f2.z, f2.w);
            half4 h2 = { hc[0], hc[1], hd[0], hd[1] };
            a3f[mt][kt] = h2;
        }
    }

    // ---- layer 1 (bias-seeded): D[o][q] over this wave's 32 q rows ----
    floatx4 d1[2][2];
    #pragma unroll
    for (int mt = 0; mt < 2; mt++) {
        float4 bb = *(const float4*)&sm.bl1[mt*16 + quad*4];
        floatx4 seed = { bb.x, bb.y, bb.z, bb.w };
        d1[mt][0] = seed; d1[mt][1] = seed;
    }
    #pragma unroll
    for (int nt = 0; nt < 2; nt++)
        #pragma unroll
        for (int kt = 0; kt < 4; kt++) {
            half4 b1 = *(const half4*)&sm.u.xs[(w*32+nt*16+L15)*72 + kt*16 + quad*4];
            d1[0][nt] = MFMA16(a1f[0][kt], b1, d1[0][nt], 0,0,0);
            d1[1][nt] = MFMA16(a1f[1][kt], b1, d1[1][nt], 0,0,0);
        }
    half4 h1b[2][2];   // C layout == next layer's B layout: in-register chain
    #pragma unroll
    for (int mt = 0; mt < 2; mt++)
        #pragma unroll
        for (int nt = 0; nt < 2; nt++) {
            float v0 = d1[mt][nt][0]; v0 = (v0>=0.f)?v0:NEG*v0;
            float v1 = d1[mt][nt][1]; v1 = (v1>=0.f)?v1:NEG*v1;
            float v2 = d1[mt][nt][2]; v2 = (v2>=0.f)?v2:NEG*v2;
            float v3 = d1[mt][nt][3]; v3 = (v3>=0.f)?v3:NEG*v3;
            half2 ha = pkcvt(v0, v1);
            half2 hb = pkcvt(v2, v3);
            half4 h = { ha[0], ha[1], hb[0], hb[1] };
            h1b[mt][nt] = h;
        }
    floatx4 d2[2][2];
    #pragma unroll
    for (int mt = 0; mt < 2; mt++) {
        float4 bb = *(const float4*)&sm.bl10[mt*16 + quad*4];
        floatx4 seed = { bb.x, bb.y, bb.z, bb.w };
        d2[mt][0] = seed; d2[mt][1] = seed;
    }
    #pragma unroll
    for (int mt = 0; mt < 2; mt++)
        #pragma unroll
        for (int nt = 0; nt < 2; nt++)
            #pragma unroll
            for (int kt = 0; kt < 2; kt++)
                d2[mt][nt] = MFMA16(a2f[mt][kt], h1b[kt][nt], d2[mt][nt], 0,0,0);
    half4 h2b[2][2];
    #pragma unroll
    for (int mt = 0; mt < 2; mt++)
        #pragma unroll
        for (int nt = 0; nt < 2; nt++) {
            float v0 = d2[mt][nt][0]; v0 = (v0>=0.f)?v0:NEG*v0;
            float v1 = d2[mt][nt][1]; v1 = (v1>=0.f)?v1:NEG*v1;
            float v2 = d2[mt][nt][2]; v2 = (v2>=0.f)?v2:NEG*v2;
            float v3 = d2[mt][nt][3]; v3 = (v3>=0.f)?v3:NEG*v3;
            half2 ha = pkcvt(v0, v1);
            half2 hb = pkcvt(v2, v3);
            half4 h = { ha[0], ha[1], hb[0], hb[1] };
            h2b[mt][nt] = h;
        }
    floatx4 d3[2][2];
    #pragma unroll
    for (int mt = 0; mt < 2; mt++) {
        float4 bb = *(const float4*)&sm.bl11[mt*16 + quad*4];
        floatx4 seed = { bb.x, bb.y, bb.z, bb.w };
        d3[mt][0] = seed; d3[mt][1] = seed;
    }
    #pragma unroll
    for (int mt = 0; mt < 2; mt++)
        #pragma unroll
        for (int nt = 0; nt < 2; nt++)
            #pragma unroll
            for (int kt = 0; kt < 2; kt++)
                d3[mt][nt] = MFMA16(a3f[mt][kt], h2b[kt][nt], d3[mt][nt], 0,0,0);
    // store: lane holds out[q=qbase+w*32+nt*16+L15][o=mt*16+quad*4+r] -> float4
    #pragma unroll
    for (int mt = 0; mt < 2; mt++)
        #pragma unroll
        for (int nt = 0; nt < 2; nt++) {
            float4 ov;
            ov.x = d3[mt][nt][0]; ov.x = (ov.x>=0.f)?ov.x:NEG*ov.x;
            ov.y = d3[mt][nt][1]; ov.y = (ov.y>=0.f)?ov.y:NEG*ov.y;
            ov.z = d3[mt][nt][2]; ov.z = (ov.z>=0.f)?ov.z:NEG*ov.z;
            ov.w = d3[mt][nt][3]; ov.w = (ov.w>=0.f)?ov.w:NEG*ov.w;
            *(float4*)(out + ((size_t)b*N_ + qbase + w*32 + nt*16 + L15)*64 + g*32 + mt*16 + quad*4) = ov;
        }
}

extern "C" void kernel_launch(void* const* d_in, const int* in_sizes, int n_in,
                              void* d_out, int out_size, void* d_ws, size_t ws_size,
                              hipStream_t stream) {
    const float* x_e   = (const float*)d_in[0];
    const float* w_qkv = (const float*)d_in[1];
    const float* b_qkv = (const float*)d_in[2];
    const float* w_h1  = (const float*)d_in[3];
    const float* b_h1  = (const float*)d_in[4];
    const float* w_h10 = (const float*)d_in[5];
    const float* b_h10 = (const float*)d_in[6];
    const float* w_h11 = (const float*)d_in[7];
    const float* b_h11 = (const float*)d_in[8];
    float* out = (float*)d_out;

    hipLaunchKernelGGL(fused_kernel, dim3(B_*2*8), dim3(256), 0, stream,
                       x_e, w_qkv, b_qkv, w_h1, b_h1, w_h10, b_h10, w_h11, b_h11, out);
}